// Round 12
// baseline (342.751 us; speedup 1.0000x reference)
//
#include <hip/hip_runtime.h>
#include <stdint.h>

typedef _Float16 f16x8 __attribute__((ext_vector_type(8)));
typedef float floatx4 __attribute__((ext_vector_type(4)));
typedef unsigned int u32x4 __attribute__((ext_vector_type(4)));

#define RR 147456   // 384*384 rows
#define NC 128      // channels
#define NN 384
// chunk-interleaved layout for at/bt/gate/o16:
//   addr(pos, c) = (pos>>6)*8192 + c*64 + (pos&63)   [fp16 units]

__device__ inline floatx4 zero4() { floatx4 v; v[0]=0.f; v[1]=0.f; v[2]=0.f; v[3]=0.f; return v; }
__device__ inline float sigmoidf_(float x) { return 1.f / (1.f + __expf(-x)); }

// ---------------------------------------------------------------------------
// k0: repack six fp32 128x128 weights into fp16 FRAGMENT-MAJOR order (as r5).
// ---------------------------------------------------------------------------
__global__ __launch_bounds__(256) void k0_wt(
    const float* __restrict__ w0, const float* __restrict__ w1,
    const float* __restrict__ w2, const float* __restrict__ w3,
    const float* __restrict__ w4, const float* __restrict__ w5,
    _Float16* __restrict__ wf)
{
  const float* w;
  switch (blockIdx.x) {
    case 0: w = w0; break; case 1: w = w1; break; case 2: w = w2; break;
    case 3: w = w3; break; case 4: w = w4; break; default: w = w5; break;
  }
  _Float16* out = wf + blockIdx.x * 16384;
  const int t = threadIdx.x;
  for (int it = 0; it < 64; ++it) {
    int f = it * 256 + t;
    int j  = f & 7;
    int ln = (f >> 3) & 63;
    int nt = (f >> 9) & 7;
    int k0 = f >> 12;
    int k = k0 * 32 + (ln >> 4) * 8 + j;
    int n = nt * 16 + (ln & 15);
    out[f] = (_Float16)w[k * 128 + n];
  }
}

// ---------------------------------------------------------------------------
// k2: LN1 -> 5 N-split GEMMs, double-buffered weight prefetch (r11, 74.9us).
// NEW r12: launch_bounds (256,3)->(256,4). VGPR_Count=80 << 128-reg cap for
// 4 blocks/CU, so the extra resident block is free concurrency (occupancy
// was 26.5% = ~2 blocks/CU; latency-bound kernel wants more TLP).
// ---------------------------------------------------------------------------
__global__ __launch_bounds__(256, 4) void k2_ln_gemm(
    const float* __restrict__ z, const float* __restrict__ ln1g, const float* __restrict__ ln1b,
    const _Float16* __restrict__ wf,
    const float* __restrict__ ba, const float* __restrict__ bga,
    const float* __restrict__ bb, const float* __restrict__ bgb,
    const float* __restrict__ bg,
    _Float16* __restrict__ at, _Float16* __restrict__ bt, _Float16* __restrict__ gate)
{
  __shared__ __align__(16) _Float16 zns[64][136];    // zn tile, padded stride
  __shared__ __align__(16) _Float16 bnc[4][32 * 72]; // per-wave store bounce
  const int t = threadIdx.x;
  const int w = t >> 6, lane = t & 63;
  const int l15 = lane & 15, quad = lane >> 4;
  const int r0 = blockIdx.x * 64;
  const int nt0 = w * 2;

  // ---- LN1 (16-lane-group reduce)
  {
    const int g = lane >> 4, h = lane & 15;
    float4 ga = *(const float4*)(ln1g + h*8);
    float4 gb = *(const float4*)(ln1g + h*8 + 4);
    float4 bba = *(const float4*)(ln1b + h*8);
    float4 bbb = *(const float4*)(ln1b + h*8 + 4);
    #pragma unroll
    for (int rr = 0; rr < 4; ++rr) {
      int row = w * 16 + rr * 4 + g;
      const float* zp = z + (size_t)(r0 + row) * NC + h * 8;
      float4 xa = *(const float4*)zp;
      float4 xb = *(const float4*)(zp + 4);
      float s = xa.x + xa.y + xa.z + xa.w + xb.x + xb.y + xb.z + xb.w;
      float q = xa.x*xa.x + xa.y*xa.y + xa.z*xa.z + xa.w*xa.w
              + xb.x*xb.x + xb.y*xb.y + xb.z*xb.z + xb.w*xb.w;
      #pragma unroll
      for (int m = 1; m < 16; m <<= 1) { s += __shfl_xor(s, m); q += __shfl_xor(q, m); }
      float mean = s * (1.f/128.f);
      float var  = q * (1.f/128.f) - mean*mean;
      float rs = rsqrtf(var + 1e-5f);
      union { uint4 u; _Float16 hh[8]; } pk;
      pk.hh[0] = (_Float16)((xa.x - mean) * rs * ga.x + bba.x);
      pk.hh[1] = (_Float16)((xa.y - mean) * rs * ga.y + bba.y);
      pk.hh[2] = (_Float16)((xa.z - mean) * rs * ga.z + bba.z);
      pk.hh[3] = (_Float16)((xa.w - mean) * rs * ga.w + bba.w);
      pk.hh[4] = (_Float16)((xb.x - mean) * rs * gb.x + bbb.x);
      pk.hh[5] = (_Float16)((xb.y - mean) * rs * gb.y + bbb.y);
      pk.hh[6] = (_Float16)((xb.z - mean) * rs * gb.z + bbb.z);
      pk.hh[7] = (_Float16)((xb.w - mean) * rs * gb.w + bbb.w);
      *(uint4*)&zns[row][h * 8] = pk.u;
    }
  }
  __syncthreads();

  const _Float16* pw = wf + lane * 8;
  f16x8 bwA[4][2], bwB[4][2];       // double-buffered weights
  floatx4 acc[4][2];
  union PkU { unsigned int u; _Float16 h[2]; };
  PkU sig[4][2][2];

  auto loadw = [&](f16x8 (&bw)[4][2], int slot) {
    const _Float16* p = pw + slot * 16384;
    #pragma unroll
    for (int k0 = 0; k0 < 4; ++k0)
      #pragma unroll
      for (int j = 0; j < 2; ++j)
        bw[k0][j] = *(const f16x8*)(p + (k0*8 + nt0 + j) * 512);
  };
  auto dogemm = [&](const f16x8 (&bw)[4][2]) {
    #pragma unroll
    for (int mt = 0; mt < 4; ++mt) {
      acc[mt][0] = zero4(); acc[mt][1] = zero4();
      #pragma unroll
      for (int k0 = 0; k0 < 4; ++k0) {
        f16x8 af = *(const f16x8*)&zns[mt*16 + l15][k0*32 + quad*8];
        acc[mt][0] = __builtin_amdgcn_mfma_f32_16x16x32_f16(af, bw[k0][0], acc[mt][0], 0, 0, 0);
        acc[mt][1] = __builtin_amdgcn_mfma_f32_16x16x32_f16(af, bw[k0][1], acc[mt][1], 0, 0, 0);
      }
    }
  };
  auto sigpack = [&](const float* big) {
    #pragma unroll
    for (int j = 0; j < 2; ++j) {
      float bgv = big[(nt0 + j)*16 + l15];
      #pragma unroll
      for (int mt = 0; mt < 4; ++mt) {
        sig[mt][j][0].h[0] = (_Float16)sigmoidf_(acc[mt][j][0] + bgv);
        sig[mt][j][0].h[1] = (_Float16)sigmoidf_(acc[mt][j][1] + bgv);
        sig[mt][j][1].h[0] = (_Float16)sigmoidf_(acc[mt][j][2] + bgv);
        sig[mt][j][1].h[1] = (_Float16)sigmoidf_(acc[mt][j][3] + bgv);
      }
    }
  };
  auto bounce_out = [&](_Float16* dst) {
    asm volatile("s_waitcnt lgkmcnt(0)" ::: "memory");
    _Float16* base = dst + (size_t)blockIdx.x * 8192 + w * 2048;
    #pragma unroll
    for (int i = 0; i < 4; ++i) {
      int f = i * 512 + lane * 8;
      int cp = f >> 6, pos = f & 63;
      u32x4 v = *(const u32x4*)&bnc[w][cp * 72 + pos];
      __builtin_nontemporal_store(v, (u32x4*)(base + f));
    }
  };
  auto combine_store = [&](const float* bia, _Float16* dst) {
    #pragma unroll
    for (int j = 0; j < 2; ++j) {
      int c = (nt0 + j)*16 + l15;
      float bav = bia[c];
      #pragma unroll
      for (int mt = 0; mt < 4; ++mt) {
        union { uint2 u2; _Float16 h[4]; } pk;
        pk.h[0] = (_Float16)((acc[mt][j][0] + bav) * (float)sig[mt][j][0].h[0]);
        pk.h[1] = (_Float16)((acc[mt][j][1] + bav) * (float)sig[mt][j][0].h[1]);
        pk.h[2] = (_Float16)((acc[mt][j][2] + bav) * (float)sig[mt][j][1].h[0]);
        pk.h[3] = (_Float16)((acc[mt][j][3] + bav) * (float)sig[mt][j][1].h[1]);
        *(uint2*)&bnc[w][(j*16 + l15) * 72 + mt*16 + quad*4] = pk.u2;
      }
    }
    bounce_out(dst);
  };

  // schedule: every loadw >=1 GEMM ahead of its consumer
  loadw(bwA, 1); loadw(bwB, 0);      // Wga, Wa in flight together
  dogemm(bwA); sigpack(bga);         // Wga
  loadw(bwA, 3);                     // Wgb (consumed 2 phases later)
  dogemm(bwB); combine_store(ba, at);// Wa
  loadw(bwB, 2);                     // Wb
  dogemm(bwA); sigpack(bgb);         // Wgb
  loadw(bwA, 4);                     // Wg
  dogemm(bwB); combine_store(bb, bt);// Wb
  dogemm(bwA);                       // Wg
  #pragma unroll
  for (int j = 0; j < 2; ++j) {
    float bgv = bg[(nt0 + j)*16 + l15];
    #pragma unroll
    for (int mt = 0; mt < 4; ++mt) {
      union { uint2 u2; _Float16 h[4]; } pk;
      #pragma unroll
      for (int r = 0; r < 4; ++r)
        pk.h[r] = (_Float16)sigmoidf_(acc[mt][j][r] + bgv);
      *(uint2*)&bnc[w][(j*16 + l15) * 72 + mt*16 + quad*4] = pk.u2;
    }
  }
  bounce_out(gate);
}

// ---------------------------------------------------------------------------
// k3: REVERTED to the r8 structure (r9's 128-thread 64x128 rewrite cost
// ~20us by halving resident waves 16->8 per CU). 256 threads, 4 waves of
// 64x64, K-step 32, P/Q register staging, ONE barrier per K-step, stride-40
// LDS (2-way max conflict), 40KB LDS -> 4 blocks/CU = 16 waves. Chunk-layout
// reads; NT chunk-layout o16 stores. Grid (9,128).
// ---------------------------------------------------------------------------
__global__ __launch_bounds__(256, 3) void k3_tri(
    const _Float16* __restrict__ at, const _Float16* __restrict__ bt, _Float16* __restrict__ o)
{
  __shared__ __align__(16) _Float16 As[2][128 * 40];
  __shared__ __align__(16) _Float16 Bs[2][128 * 40];
  const int t = threadIdx.x;
  const int w = t >> 6, lane = t & 63, l15 = lane & 15, quad = lane >> 4;
  const int c = blockIdx.y;
  const int i0 = (blockIdx.x / 3) * 128, j0 = (blockIdx.x % 3) * 128;
  const int wi = w >> 1, wj = w & 1;

  // staging: row = t>>1 (0..127), half = (t&1)*16 fp16 (32B); 64B/row/step
  const int srow = t >> 1, sch = (t & 1) * 16;
  const _Float16* gaRow = at + (size_t)(i0 + srow) * 6 * 8192 + (size_t)c * 64;
  const _Float16* gbRow = bt + (size_t)(j0 + srow) * 6 * 8192 + (size_t)c * 64;
  _Float16* const pa0 = &As[0][srow * 40 + sch];
  _Float16* const pb0 = &Bs[0][srow * 40 + sch];
  _Float16* const pa1 = &As[1][srow * 40 + sch];
  _Float16* const pb1 = &Bs[1][srow * 40 + sch];

  floatx4 acc[4][4];
  #pragma unroll
  for (int mt = 0; mt < 4; ++mt)
    #pragma unroll
    for (int nt = 0; nt < 4; ++nt) acc[mt][nt] = zero4();

  f16x8 aP0,aP1,bP0,bP1, aQ0,aQ1,bQ0,bQ1;

  auto gofs = [&](int kk) -> size_t {
    int x = kk + sch;                       // within-row k offset
    return (size_t)(x >> 6) * 8192 + (size_t)(x & 63);
  };
  auto gloadP = [&](int kk) {
    size_t go = gofs(kk);
    aP0 = *(const f16x8*)(gaRow + go); aP1 = *(const f16x8*)(gaRow + go + 8);
    bP0 = *(const f16x8*)(gbRow + go); bP1 = *(const f16x8*)(gbRow + go + 8);
  };
  auto gloadQ = [&](int kk) {
    size_t go = gofs(kk);
    aQ0 = *(const f16x8*)(gaRow + go); aQ1 = *(const f16x8*)(gaRow + go + 8);
    bQ0 = *(const f16x8*)(gbRow + go); bQ1 = *(const f16x8*)(gbRow + go + 8);
  };
  auto swriteP = [&](int buf) {
    _Float16* pa = buf ? pa1 : pa0; _Float16* pb = buf ? pb1 : pb0;
    *(f16x8*)pa = aP0; *(f16x8*)(pa + 8) = aP1;
    *(f16x8*)pb = bP0; *(f16x8*)(pb + 8) = bP1;
  };
  auto swriteQ = [&](int buf) {
    _Float16* pa = buf ? pa1 : pa0; _Float16* pb = buf ? pb1 : pb0;
    *(f16x8*)pa = aQ0; *(f16x8*)(pa + 8) = aQ1;
    *(f16x8*)pb = bQ0; *(f16x8*)(pb + 8) = bQ1;
  };
  auto compute = [&](int buf) {
    f16x8 af[4], bfr[4];
    #pragma unroll
    for (int mt = 0; mt < 4; ++mt)
      af[mt] = *(const f16x8*)&As[buf][(wi*64 + mt*16 + l15) * 40 + quad*8];
    #pragma unroll
    for (int nt = 0; nt < 4; ++nt)
      bfr[nt] = *(const f16x8*)&Bs[buf][(wj*64 + nt*16 + l15) * 40 + quad*8];
    #pragma unroll
    for (int mt = 0; mt < 4; ++mt)
      #pragma unroll
      for (int nt = 0; nt < 4; ++nt)
        acc[mt][nt] = __builtin_amdgcn_mfma_f32_16x16x32_f16(af[mt], bfr[nt], acc[mt][nt], 0, 0, 0);
  };

  // 12 K-steps of 32. step s lives in buf[s&1].
  gloadP(0); swriteP(0); gloadP(32);
  __syncthreads();
  #pragma unroll
  for (int s = 0; s < 12; s += 2) {
    if (s + 2 < 12) gloadQ((s + 2) * 32);   // in flight during compute
    compute(0);
    swriteP(1);                              // step s+1 -> buf1
    __syncthreads();
    if (s + 3 < 12) gloadP((s + 3) * 32);
    compute(1);
    if (s + 2 < 12) { swriteQ(0); __syncthreads(); }
  }

  // store o16 in chunk layout, NONTEMPORAL; 32B runs per (mt,r,nt)
  #pragma unroll
  for (int mt = 0; mt < 4; ++mt) {
    #pragma unroll
    for (int r = 0; r < 4; ++r) {
      int i = i0 + wi*64 + mt*16 + quad*4 + r;
      _Float16* obase = o + (size_t)(i*6 + (j0 >> 6) + wj) * 8192 + (size_t)c * 64;
      #pragma unroll
      for (int nt = 0; nt < 4; ++nt)
        __builtin_nontemporal_store((_Float16)acc[mt][nt][r], obase + nt*16 + l15);
    }
  }
}

// ---------------------------------------------------------------------------
// k4: Wo-fragment and gate loads hoisted to the TOP (independent of the o16
// pipeline) so the post-LN2 tail has zero cold loads. (unchanged from r11)
// ---------------------------------------------------------------------------
__global__ __launch_bounds__(256, 4) void k4_out(
    const _Float16* __restrict__ o, const _Float16* __restrict__ gate,
    const float* __restrict__ ln2g, const float* __restrict__ ln2b,
    const _Float16* __restrict__ wo5, const float* __restrict__ bo,
    float* __restrict__ out)
{
  __shared__ __align__(16) _Float16 osb[64][136];
  const int t = threadIdx.x;
  const int w = t >> 6, lane = t & 63, l15 = lane & 15, quad = lane >> 4;
  const int r0 = blockIdx.x * 64;
  const int nt0 = w * 2;

  // hoisted: weights + gate (both independent of o16)
  f16x8 bw[4][2];
  {
    const _Float16* p = wo5 + lane * 8;
    #pragma unroll
    for (int k0 = 0; k0 < 4; ++k0)
      #pragma unroll
      for (int j = 0; j < 2; ++j)
        bw[k0][j] = *(const f16x8*)(p + (k0*8 + nt0 + j) * 512);
  }
  union GkU { uint2 u2; _Float16 h[4]; };
  GkU gk[2][4];
  #pragma unroll
  for (int j = 0; j < 2; ++j) {
    int cch = (nt0 + j)*16 + l15;
    #pragma unroll
    for (int mt = 0; mt < 4; ++mt)
      gk[j][mt].u2 = *(const uint2*)(gate + (size_t)blockIdx.x * 8192 + (size_t)cch * 64 + mt*16 + quad*4);
  }

  // gather o16 chunk -> LDS transpose
  {
    const _Float16* ob = o + (size_t)blockIdx.x * 8192;
    #pragma unroll
    for (int it = 0; it < 4; ++it) {
      int f = (it * 256 + t) * 8;
      int cx = f >> 6, p = f & 63;
      f16x8 v = *(const f16x8*)(ob + f);
      #pragma unroll
      for (int i = 0; i < 8; ++i) osb[p + i][cx] = v[i];
    }
  }
  __syncthreads();

  // LN2 in place
  {
    const int g = lane >> 4, h = lane & 15;
    float4 ga = *(const float4*)(ln2g + h*8);
    float4 gb = *(const float4*)(ln2g + h*8 + 4);
    float4 bba = *(const float4*)(ln2b + h*8);
    float4 bbb = *(const float4*)(ln2b + h*8 + 4);
    #pragma unroll
    for (int rr = 0; rr < 4; ++rr) {
      int row = w * 16 + rr * 4 + g;
      f16x8 xv = *(const f16x8*)&osb[row][h*8];
      float x0 = (float)xv[0], x1 = (float)xv[1], x2 = (float)xv[2], x3 = (float)xv[3];
      float x4 = (float)xv[4], x5 = (float)xv[5], x6 = (float)xv[6], x7 = (float)xv[7];
      float s = x0+x1+x2+x3+x4+x5+x6+x7;
      float q = x0*x0+x1*x1+x2*x2+x3*x3+x4*x4+x5*x5+x6*x6+x7*x7;
      #pragma unroll
      for (int m = 1; m < 16; m <<= 1) { s += __shfl_xor(s, m); q += __shfl_xor(q, m); }
      float mean = s * (1.f/128.f);
      float var  = q * (1.f/128.f) - mean*mean;
      float rs = rsqrtf(var + 1e-5f);
      union { uint4 u; _Float16 hh[8]; } pk;
      pk.hh[0] = (_Float16)((x0 - mean) * rs * ga.x + bba.x);
      pk.hh[1] = (_Float16)((x1 - mean) * rs * ga.y + bba.y);
      pk.hh[2] = (_Float16)((x2 - mean) * rs * ga.z + bba.z);
      pk.hh[3] = (_Float16)((x3 - mean) * rs * ga.w + bba.w);
      pk.hh[4] = (_Float16)((x4 - mean) * rs * gb.x + bbb.x);
      pk.hh[5] = (_Float16)((x5 - mean) * rs * gb.y + bbb.y);
      pk.hh[6] = (_Float16)((x6 - mean) * rs * gb.z + bbb.z);
      pk.hh[7] = (_Float16)((x7 - mean) * rs * gb.w + bbb.w);
      *(uint4*)&osb[row][h * 8] = pk.u;
    }
  }
  __syncthreads();

  floatx4 acc[4][2];
  #pragma unroll
  for (int mt = 0; mt < 4; ++mt) {
    acc[mt][0] = zero4(); acc[mt][1] = zero4();
    #pragma unroll
    for (int k0 = 0; k0 < 4; ++k0) {
      f16x8 af = *(const f16x8*)&osb[mt*16 + l15][k0*32 + quad*8];
      acc[mt][0] = __builtin_amdgcn_mfma_f32_16x16x32_f16(af, bw[k0][0], acc[mt][0], 0, 0, 0);
      acc[mt][1] = __builtin_amdgcn_mfma_f32_16x16x32_f16(af, bw[k0][1], acc[mt][1], 0, 0, 0);
    }
  }

  #pragma unroll
  for (int j = 0; j < 2; ++j) {
    int cch = (nt0 + j)*16 + l15;
    float bov = bo[cch];
    #pragma unroll
    for (int mt = 0; mt < 4; ++mt) {
      #pragma unroll
      for (int r = 0; r < 4; ++r) {
        int rl = mt*16 + quad*4 + r;
        __builtin_nontemporal_store((float)gk[j][mt].h[r] * (acc[mt][j][r] + bov),
                                    out + (size_t)(r0 + rl) * NC + cch);
      }
    }
  }
}

// ---------------------------------------------------------------------------
// Workspace layout (bytes): as round 8 (all chunk-layout fp16 + wf).
// ---------------------------------------------------------------------------
extern "C" void kernel_launch(void* const* d_in, const int* in_sizes, int n_in,
                              void* d_out, int out_size, void* d_ws, size_t ws_size,
                              hipStream_t stream) {
  const float* z    = (const float*)d_in[0];
  const float* l1g  = (const float*)d_in[1];
  const float* l1b  = (const float*)d_in[2];
  const float* l2g  = (const float*)d_in[3];
  const float* l2b  = (const float*)d_in[4];
  const float* Wa   = (const float*)d_in[5];
  const float* ba   = (const float*)d_in[6];
  const float* Wga  = (const float*)d_in[7];
  const float* bga  = (const float*)d_in[8];
  const float* Wb   = (const float*)d_in[9];
  const float* bb   = (const float*)d_in[10];
  const float* Wgb  = (const float*)d_in[11];
  const float* bgb  = (const float*)d_in[12];
  const float* Wg   = (const float*)d_in[13];
  const float* bg   = (const float*)d_in[14];
  const float* Wo   = (const float*)d_in[15];
  const float* bo   = (const float*)d_in[16];

  char* ws = (char*)d_ws;
  _Float16* at_  = (_Float16*)(ws + 0);
  _Float16* bt_  = (_Float16*)(ws + 37748736);
  _Float16* gate = (_Float16*)(ws + 75497472);
  _Float16* o16  = (_Float16*)(ws + 113246208);
  _Float16* wf   = (_Float16*)(ws + 188743680);

  hipLaunchKernelGGL(k0_wt, dim3(6), dim3(256), 0, stream, Wa, Wga, Wb, Wgb, Wg, Wo, wf);
  hipLaunchKernelGGL(k2_ln_gemm, dim3(2304), dim3(256), 0, stream,
                     z, l1g, l1b, wf, ba, bga, bb, bgb, bg, at_, bt_, gate);
  hipLaunchKernelGGL(k3_tri, dim3(9, 128), dim3(256), 0, stream, at_, bt_, o16);
  hipLaunchKernelGGL(k4_out, dim3(2304), dim3(256), 0, stream,
                     o16, gate, l2g, l2b, wf + 5*16384, bo, (float*)d_out);
}

// Round 13
// 303.860 us; speedup vs baseline: 1.1280x; 1.1280x over previous
//
#include <hip/hip_runtime.h>
#include <stdint.h>

typedef _Float16 f16x8 __attribute__((ext_vector_type(8)));
typedef float floatx4 __attribute__((ext_vector_type(4)));
typedef unsigned int u32x4 __attribute__((ext_vector_type(4)));

#define RR 147456   // 384*384 rows
#define NC 128      // channels
#define NN 384
// chunk-interleaved layout for at/bt/gate/o16:
//   addr(pos, c) = (pos>>6)*8192 + c*64 + (pos&63)   [fp16 units]

__device__ inline floatx4 zero4() { floatx4 v; v[0]=0.f; v[1]=0.f; v[2]=0.f; v[3]=0.f; return v; }
__device__ inline float sigmoidf_(float x) { return 1.f / (1.f + __expf(-x)); }

// ---------------------------------------------------------------------------
// k0: repack six fp32 128x128 weights into fp16 FRAGMENT-MAJOR order (as r5).
// ---------------------------------------------------------------------------
__global__ __launch_bounds__(256) void k0_wt(
    const float* __restrict__ w0, const float* __restrict__ w1,
    const float* __restrict__ w2, const float* __restrict__ w3,
    const float* __restrict__ w4, const float* __restrict__ w5,
    _Float16* __restrict__ wf)
{
  const float* w;
  switch (blockIdx.x) {
    case 0: w = w0; break; case 1: w = w1; break; case 2: w = w2; break;
    case 3: w = w3; break; case 4: w = w4; break; default: w = w5; break;
  }
  _Float16* out = wf + blockIdx.x * 16384;
  const int t = threadIdx.x;
  for (int it = 0; it < 64; ++it) {
    int f = it * 256 + t;
    int j  = f & 7;
    int ln = (f >> 3) & 63;
    int nt = (f >> 9) & 7;
    int k0 = f >> 12;
    int k = k0 * 32 + (ln >> 4) * 8 + j;
    int n = nt * 16 + (ln & 15);
    out[f] = (_Float16)w[k * 128 + n];
  }
}

// ---------------------------------------------------------------------------
// k2: EXACT r11 (74.9us measured). (256,3): the schedule needs ~112 live
// regs (bwA+bwB+acc+sig); r12's (256,4) forced 64-reg allocation, which
// serialized the weight prefetch and regressed to 110us + write-amp.
// Registers-for-prefetch > TLP for this kernel.
// ---------------------------------------------------------------------------
__global__ __launch_bounds__(256, 3) void k2_ln_gemm(
    const float* __restrict__ z, const float* __restrict__ ln1g, const float* __restrict__ ln1b,
    const _Float16* __restrict__ wf,
    const float* __restrict__ ba, const float* __restrict__ bga,
    const float* __restrict__ bb, const float* __restrict__ bgb,
    const float* __restrict__ bg,
    _Float16* __restrict__ at, _Float16* __restrict__ bt, _Float16* __restrict__ gate)
{
  __shared__ __align__(16) _Float16 zns[64][136];    // zn tile, padded stride
  __shared__ __align__(16) _Float16 bnc[4][32 * 72]; // per-wave store bounce
  const int t = threadIdx.x;
  const int w = t >> 6, lane = t & 63;
  const int l15 = lane & 15, quad = lane >> 4;
  const int r0 = blockIdx.x * 64;
  const int nt0 = w * 2;

  // ---- LN1 (16-lane-group reduce)
  {
    const int g = lane >> 4, h = lane & 15;
    float4 ga = *(const float4*)(ln1g + h*8);
    float4 gb = *(const float4*)(ln1g + h*8 + 4);
    float4 bba = *(const float4*)(ln1b + h*8);
    float4 bbb = *(const float4*)(ln1b + h*8 + 4);
    #pragma unroll
    for (int rr = 0; rr < 4; ++rr) {
      int row = w * 16 + rr * 4 + g;
      const float* zp = z + (size_t)(r0 + row) * NC + h * 8;
      float4 xa = *(const float4*)zp;
      float4 xb = *(const float4*)(zp + 4);
      float s = xa.x + xa.y + xa.z + xa.w + xb.x + xb.y + xb.z + xb.w;
      float q = xa.x*xa.x + xa.y*xa.y + xa.z*xa.z + xa.w*xa.w
              + xb.x*xb.x + xb.y*xb.y + xb.z*xb.z + xb.w*xb.w;
      #pragma unroll
      for (int m = 1; m < 16; m <<= 1) { s += __shfl_xor(s, m); q += __shfl_xor(q, m); }
      float mean = s * (1.f/128.f);
      float var  = q * (1.f/128.f) - mean*mean;
      float rs = rsqrtf(var + 1e-5f);
      union { uint4 u; _Float16 hh[8]; } pk;
      pk.hh[0] = (_Float16)((xa.x - mean) * rs * ga.x + bba.x);
      pk.hh[1] = (_Float16)((xa.y - mean) * rs * ga.y + bba.y);
      pk.hh[2] = (_Float16)((xa.z - mean) * rs * ga.z + bba.z);
      pk.hh[3] = (_Float16)((xa.w - mean) * rs * ga.w + bba.w);
      pk.hh[4] = (_Float16)((xb.x - mean) * rs * gb.x + bbb.x);
      pk.hh[5] = (_Float16)((xb.y - mean) * rs * gb.y + bbb.y);
      pk.hh[6] = (_Float16)((xb.z - mean) * rs * gb.z + bbb.z);
      pk.hh[7] = (_Float16)((xb.w - mean) * rs * gb.w + bbb.w);
      *(uint4*)&zns[row][h * 8] = pk.u;
    }
  }
  __syncthreads();

  const _Float16* pw = wf + lane * 8;
  f16x8 bwA[4][2], bwB[4][2];       // double-buffered weights
  floatx4 acc[4][2];
  union PkU { unsigned int u; _Float16 h[2]; };
  PkU sig[4][2][2];

  auto loadw = [&](f16x8 (&bw)[4][2], int slot) {
    const _Float16* p = pw + slot * 16384;
    #pragma unroll
    for (int k0 = 0; k0 < 4; ++k0)
      #pragma unroll
      for (int j = 0; j < 2; ++j)
        bw[k0][j] = *(const f16x8*)(p + (k0*8 + nt0 + j) * 512);
  };
  auto dogemm = [&](const f16x8 (&bw)[4][2]) {
    #pragma unroll
    for (int mt = 0; mt < 4; ++mt) {
      acc[mt][0] = zero4(); acc[mt][1] = zero4();
      #pragma unroll
      for (int k0 = 0; k0 < 4; ++k0) {
        f16x8 af = *(const f16x8*)&zns[mt*16 + l15][k0*32 + quad*8];
        acc[mt][0] = __builtin_amdgcn_mfma_f32_16x16x32_f16(af, bw[k0][0], acc[mt][0], 0, 0, 0);
        acc[mt][1] = __builtin_amdgcn_mfma_f32_16x16x32_f16(af, bw[k0][1], acc[mt][1], 0, 0, 0);
      }
    }
  };
  auto sigpack = [&](const float* big) {
    #pragma unroll
    for (int j = 0; j < 2; ++j) {
      float bgv = big[(nt0 + j)*16 + l15];
      #pragma unroll
      for (int mt = 0; mt < 4; ++mt) {
        sig[mt][j][0].h[0] = (_Float16)sigmoidf_(acc[mt][j][0] + bgv);
        sig[mt][j][0].h[1] = (_Float16)sigmoidf_(acc[mt][j][1] + bgv);
        sig[mt][j][1].h[0] = (_Float16)sigmoidf_(acc[mt][j][2] + bgv);
        sig[mt][j][1].h[1] = (_Float16)sigmoidf_(acc[mt][j][3] + bgv);
      }
    }
  };
  auto bounce_out = [&](_Float16* dst) {
    asm volatile("s_waitcnt lgkmcnt(0)" ::: "memory");
    _Float16* base = dst + (size_t)blockIdx.x * 8192 + w * 2048;
    #pragma unroll
    for (int i = 0; i < 4; ++i) {
      int f = i * 512 + lane * 8;
      int cp = f >> 6, pos = f & 63;
      u32x4 v = *(const u32x4*)&bnc[w][cp * 72 + pos];
      __builtin_nontemporal_store(v, (u32x4*)(base + f));
    }
  };
  auto combine_store = [&](const float* bia, _Float16* dst) {
    #pragma unroll
    for (int j = 0; j < 2; ++j) {
      int c = (nt0 + j)*16 + l15;
      float bav = bia[c];
      #pragma unroll
      for (int mt = 0; mt < 4; ++mt) {
        union { uint2 u2; _Float16 h[4]; } pk;
        pk.h[0] = (_Float16)((acc[mt][j][0] + bav) * (float)sig[mt][j][0].h[0]);
        pk.h[1] = (_Float16)((acc[mt][j][1] + bav) * (float)sig[mt][j][0].h[1]);
        pk.h[2] = (_Float16)((acc[mt][j][2] + bav) * (float)sig[mt][j][1].h[0]);
        pk.h[3] = (_Float16)((acc[mt][j][3] + bav) * (float)sig[mt][j][1].h[1]);
        *(uint2*)&bnc[w][(j*16 + l15) * 72 + mt*16 + quad*4] = pk.u2;
      }
    }
    bounce_out(dst);
  };

  // schedule: every loadw >=1 GEMM ahead of its consumer
  loadw(bwA, 1); loadw(bwB, 0);      // Wga, Wa in flight together
  dogemm(bwA); sigpack(bga);         // Wga
  loadw(bwA, 3);                     // Wgb (consumed 2 phases later)
  dogemm(bwB); combine_store(ba, at);// Wa
  loadw(bwB, 2);                     // Wb
  dogemm(bwA); sigpack(bgb);         // Wgb
  loadw(bwA, 4);                     // Wg
  dogemm(bwB); combine_store(bb, bt);// Wb
  dogemm(bwA);                       // Wg
  #pragma unroll
  for (int j = 0; j < 2; ++j) {
    float bgv = bg[(nt0 + j)*16 + l15];
    #pragma unroll
    for (int mt = 0; mt < 4; ++mt) {
      union { uint2 u2; _Float16 h[4]; } pk;
      #pragma unroll
      for (int r = 0; r < 4; ++r)
        pk.h[r] = (_Float16)sigmoidf_(acc[mt][j][r] + bgv);
      *(uint2*)&bnc[w][(j*16 + l15) * 72 + mt*16 + quad*4] = pk.u2;
    }
  }
  bounce_out(gate);
}

// ---------------------------------------------------------------------------
// k3: r8-structure (256 thr, 4 waves of 64x64, K-step 32, P/Q staging, one
// barrier per step, stride-40 LDS). NEW r13: o16 stored with REGULAR stores
// (r9-r12 used NT here; o16 is re-read by k4 one kernel later, and the NT
// hint evicts it from L2/L3, turning k4's reads into HBM fetches).
// ---------------------------------------------------------------------------
__global__ __launch_bounds__(256, 3) void k3_tri(
    const _Float16* __restrict__ at, const _Float16* __restrict__ bt, _Float16* __restrict__ o)
{
  __shared__ __align__(16) _Float16 As[2][128 * 40];
  __shared__ __align__(16) _Float16 Bs[2][128 * 40];
  const int t = threadIdx.x;
  const int w = t >> 6, lane = t & 63, l15 = lane & 15, quad = lane >> 4;
  const int c = blockIdx.y;
  const int i0 = (blockIdx.x / 3) * 128, j0 = (blockIdx.x % 3) * 128;
  const int wi = w >> 1, wj = w & 1;

  // staging: row = t>>1 (0..127), half = (t&1)*16 fp16 (32B); 64B/row/step
  const int srow = t >> 1, sch = (t & 1) * 16;
  const _Float16* gaRow = at + (size_t)(i0 + srow) * 6 * 8192 + (size_t)c * 64;
  const _Float16* gbRow = bt + (size_t)(j0 + srow) * 6 * 8192 + (size_t)c * 64;
  _Float16* const pa0 = &As[0][srow * 40 + sch];
  _Float16* const pb0 = &Bs[0][srow * 40 + sch];
  _Float16* const pa1 = &As[1][srow * 40 + sch];
  _Float16* const pb1 = &Bs[1][srow * 40 + sch];

  floatx4 acc[4][4];
  #pragma unroll
  for (int mt = 0; mt < 4; ++mt)
    #pragma unroll
    for (int nt = 0; nt < 4; ++nt) acc[mt][nt] = zero4();

  f16x8 aP0,aP1,bP0,bP1, aQ0,aQ1,bQ0,bQ1;

  auto gofs = [&](int kk) -> size_t {
    int x = kk + sch;                       // within-row k offset
    return (size_t)(x >> 6) * 8192 + (size_t)(x & 63);
  };
  auto gloadP = [&](int kk) {
    size_t go = gofs(kk);
    aP0 = *(const f16x8*)(gaRow + go); aP1 = *(const f16x8*)(gaRow + go + 8);
    bP0 = *(const f16x8*)(gbRow + go); bP1 = *(const f16x8*)(gbRow + go + 8);
  };
  auto gloadQ = [&](int kk) {
    size_t go = gofs(kk);
    aQ0 = *(const f16x8*)(gaRow + go); aQ1 = *(const f16x8*)(gaRow + go + 8);
    bQ0 = *(const f16x8*)(gbRow + go); bQ1 = *(const f16x8*)(gbRow + go + 8);
  };
  auto swriteP = [&](int buf) {
    _Float16* pa = buf ? pa1 : pa0; _Float16* pb = buf ? pb1 : pb0;
    *(f16x8*)pa = aP0; *(f16x8*)(pa + 8) = aP1;
    *(f16x8*)pb = bP0; *(f16x8*)(pb + 8) = bP1;
  };
  auto swriteQ = [&](int buf) {
    _Float16* pa = buf ? pa1 : pa0; _Float16* pb = buf ? pb1 : pb0;
    *(f16x8*)pa = aQ0; *(f16x8*)(pa + 8) = aQ1;
    *(f16x8*)pb = bQ0; *(f16x8*)(pb + 8) = bQ1;
  };
  auto compute = [&](int buf) {
    f16x8 af[4], bfr[4];
    #pragma unroll
    for (int mt = 0; mt < 4; ++mt)
      af[mt] = *(const f16x8*)&As[buf][(wi*64 + mt*16 + l15) * 40 + quad*8];
    #pragma unroll
    for (int nt = 0; nt < 4; ++nt)
      bfr[nt] = *(const f16x8*)&Bs[buf][(wj*64 + nt*16 + l15) * 40 + quad*8];
    #pragma unroll
    for (int mt = 0; mt < 4; ++mt)
      #pragma unroll
      for (int nt = 0; nt < 4; ++nt)
        acc[mt][nt] = __builtin_amdgcn_mfma_f32_16x16x32_f16(af[mt], bfr[nt], acc[mt][nt], 0, 0, 0);
  };

  // 12 K-steps of 32. step s lives in buf[s&1].
  gloadP(0); swriteP(0); gloadP(32);
  __syncthreads();
  #pragma unroll
  for (int s = 0; s < 12; s += 2) {
    if (s + 2 < 12) gloadQ((s + 2) * 32);   // in flight during compute
    compute(0);
    swriteP(1);                              // step s+1 -> buf1
    __syncthreads();
    if (s + 3 < 12) gloadP((s + 3) * 32);
    compute(1);
    if (s + 2 < 12) { swriteQ(0); __syncthreads(); }
  }

  // store o16 in chunk layout, REGULAR stores (keep L2/L3-resident for k4)
  #pragma unroll
  for (int mt = 0; mt < 4; ++mt) {
    #pragma unroll
    for (int r = 0; r < 4; ++r) {
      int i = i0 + wi*64 + mt*16 + quad*4 + r;
      _Float16* obase = o + (size_t)(i*6 + (j0 >> 6) + wj) * 8192 + (size_t)c * 64;
      #pragma unroll
      for (int nt = 0; nt < 4; ++nt)
        obase[nt*16 + l15] = (_Float16)acc[mt][nt][r];
    }
  }
}

// ---------------------------------------------------------------------------
// k4: Wo-fragment and gate loads hoisted to the TOP (independent of the o16
// pipeline) so the post-LN2 tail has zero cold loads. NT only on `out`
// (never re-read). (unchanged from r12)
// ---------------------------------------------------------------------------
__global__ __launch_bounds__(256, 4) void k4_out(
    const _Float16* __restrict__ o, const _Float16* __restrict__ gate,
    const float* __restrict__ ln2g, const float* __restrict__ ln2b,
    const _Float16* __restrict__ wo5, const float* __restrict__ bo,
    float* __restrict__ out)
{
  __shared__ __align__(16) _Float16 osb[64][136];
  const int t = threadIdx.x;
  const int w = t >> 6, lane = t & 63, l15 = lane & 15, quad = lane >> 4;
  const int r0 = blockIdx.x * 64;
  const int nt0 = w * 2;

  // hoisted: weights + gate (both independent of o16)
  f16x8 bw[4][2];
  {
    const _Float16* p = wo5 + lane * 8;
    #pragma unroll
    for (int k0 = 0; k0 < 4; ++k0)
      #pragma unroll
      for (int j = 0; j < 2; ++j)
        bw[k0][j] = *(const f16x8*)(p + (k0*8 + nt0 + j) * 512);
  }
  union GkU { uint2 u2; _Float16 h[4]; };
  GkU gk[2][4];
  #pragma unroll
  for (int j = 0; j < 2; ++j) {
    int cch = (nt0 + j)*16 + l15;
    #pragma unroll
    for (int mt = 0; mt < 4; ++mt)
      gk[j][mt].u2 = *(const uint2*)(gate + (size_t)blockIdx.x * 8192 + (size_t)cch * 64 + mt*16 + quad*4);
  }

  // gather o16 chunk -> LDS transpose
  {
    const _Float16* ob = o + (size_t)blockIdx.x * 8192;
    #pragma unroll
    for (int it = 0; it < 4; ++it) {
      int f = (it * 256 + t) * 8;
      int cx = f >> 6, p = f & 63;
      f16x8 v = *(const f16x8*)(ob + f);
      #pragma unroll
      for (int i = 0; i < 8; ++i) osb[p + i][cx] = v[i];
    }
  }
  __syncthreads();

  // LN2 in place
  {
    const int g = lane >> 4, h = lane & 15;
    float4 ga = *(const float4*)(ln2g + h*8);
    float4 gb = *(const float4*)(ln2g + h*8 + 4);
    float4 bba = *(const float4*)(ln2b + h*8);
    float4 bbb = *(const float4*)(ln2b + h*8 + 4);
    #pragma unroll
    for (int rr = 0; rr < 4; ++rr) {
      int row = w * 16 + rr * 4 + g;
      f16x8 xv = *(const f16x8*)&osb[row][h*8];
      float x0 = (float)xv[0], x1 = (float)xv[1], x2 = (float)xv[2], x3 = (float)xv[3];
      float x4 = (float)xv[4], x5 = (float)xv[5], x6 = (float)xv[6], x7 = (float)xv[7];
      float s = x0+x1+x2+x3+x4+x5+x6+x7;
      float q = x0*x0+x1*x1+x2*x2+x3*x3+x4*x4+x5*x5+x6*x6+x7*x7;
      #pragma unroll
      for (int m = 1; m < 16; m <<= 1) { s += __shfl_xor(s, m); q += __shfl_xor(q, m); }
      float mean = s * (1.f/128.f);
      float var  = q * (1.f/128.f) - mean*mean;
      float rs = rsqrtf(var + 1e-5f);
      union { uint4 u; _Float16 hh[8]; } pk;
      pk.hh[0] = (_Float16)((x0 - mean) * rs * ga.x + bba.x);
      pk.hh[1] = (_Float16)((x1 - mean) * rs * ga.y + bba.y);
      pk.hh[2] = (_Float16)((x2 - mean) * rs * ga.z + bba.z);
      pk.hh[3] = (_Float16)((x3 - mean) * rs * ga.w + bba.w);
      pk.hh[4] = (_Float16)((x4 - mean) * rs * gb.x + bbb.x);
      pk.hh[5] = (_Float16)((x5 - mean) * rs * gb.y + bbb.y);
      pk.hh[6] = (_Float16)((x6 - mean) * rs * gb.z + bbb.z);
      pk.hh[7] = (_Float16)((x7 - mean) * rs * gb.w + bbb.w);
      *(uint4*)&osb[row][h * 8] = pk.u;
    }
  }
  __syncthreads();

  floatx4 acc[4][2];
  #pragma unroll
  for (int mt = 0; mt < 4; ++mt) {
    acc[mt][0] = zero4(); acc[mt][1] = zero4();
    #pragma unroll
    for (int k0 = 0; k0 < 4; ++k0) {
      f16x8 af = *(const f16x8*)&osb[mt*16 + l15][k0*32 + quad*8];
      acc[mt][0] = __builtin_amdgcn_mfma_f32_16x16x32_f16(af, bw[k0][0], acc[mt][0], 0, 0, 0);
      acc[mt][1] = __builtin_amdgcn_mfma_f32_16x16x32_f16(af, bw[k0][1], acc[mt][1], 0, 0, 0);
    }
  }

  #pragma unroll
  for (int j = 0; j < 2; ++j) {
    int cch = (nt0 + j)*16 + l15;
    float bov = bo[cch];
    #pragma unroll
    for (int mt = 0; mt < 4; ++mt) {
      #pragma unroll
      for (int r = 0; r < 4; ++r) {
        int rl = mt*16 + quad*4 + r;
        __builtin_nontemporal_store((float)gk[j][mt].h[r] * (acc[mt][j][r] + bov),
                                    out + (size_t)(r0 + rl) * NC + cch);
      }
    }
  }
}

// ---------------------------------------------------------------------------
// Workspace layout (bytes): as round 8 (all chunk-layout fp16 + wf).
// ---------------------------------------------------------------------------
extern "C" void kernel_launch(void* const* d_in, const int* in_sizes, int n_in,
                              void* d_out, int out_size, void* d_ws, size_t ws_size,
                              hipStream_t stream) {
  const float* z    = (const float*)d_in[0];
  const float* l1g  = (const float*)d_in[1];
  const float* l1b  = (const float*)d_in[2];
  const float* l2g  = (const float*)d_in[3];
  const float* l2b  = (const float*)d_in[4];
  const float* Wa   = (const float*)d_in[5];
  const float* ba   = (const float*)d_in[6];
  const float* Wga  = (const float*)d_in[7];
  const float* bga  = (const float*)d_in[8];
  const float* Wb   = (const float*)d_in[9];
  const float* bb   = (const float*)d_in[10];
  const float* Wgb  = (const float*)d_in[11];
  const float* bgb  = (const float*)d_in[12];
  const float* Wg   = (const float*)d_in[13];
  const float* bg   = (const float*)d_in[14];
  const float* Wo   = (const float*)d_in[15];
  const float* bo   = (const float*)d_in[16];

  char* ws = (char*)d_ws;
  _Float16* at_  = (_Float16*)(ws + 0);
  _Float16* bt_  = (_Float16*)(ws + 37748736);
  _Float16* gate = (_Float16*)(ws + 75497472);
  _Float16* o16  = (_Float16*)(ws + 113246208);
  _Float16* wf   = (_Float16*)(ws + 188743680);

  hipLaunchKernelGGL(k0_wt, dim3(6), dim3(256), 0, stream, Wa, Wga, Wb, Wgb, Wg, Wo, wf);
  hipLaunchKernelGGL(k2_ln_gemm, dim3(2304), dim3(256), 0, stream,
                     z, l1g, l1b, wf, ba, bga, bb, bgb, bg, at_, bt_, gate);
  hipLaunchKernelGGL(k3_tri, dim3(9, 128), dim3(256), 0, stream, at_, bt_, o16);
  hipLaunchKernelGGL(k4_out, dim3(2304), dim3(256), 0, stream,
                     o16, gate, l2g, l2b, wf + 5*16384, bo, (float*)d_out);
}

// Round 15
// 280.106 us; speedup vs baseline: 1.2236x; 1.0848x over previous
//
#include <hip/hip_runtime.h>
#include <stdint.h>

typedef _Float16 f16x8 __attribute__((ext_vector_type(8)));
typedef float floatx4 __attribute__((ext_vector_type(4)));
typedef unsigned int u32x4 __attribute__((ext_vector_type(4)));

#define RR 147456   // 384*384 rows
#define NC 128      // channels
#define NN 384
// chunk-interleaved layout for at/bt/gate/o16:
//   addr(pos, c) = (pos>>6)*8192 + c*64 + (pos&63)   [fp16 units]

__device__ inline floatx4 zero4() { floatx4 v; v[0]=0.f; v[1]=0.f; v[2]=0.f; v[3]=0.f; return v; }
__device__ inline float sigmoidf_(float x) { return 1.f / (1.f + __expf(-x)); }

// ---------------------------------------------------------------------------
// k0: repack six fp32 128x128 weights into fp16 FRAGMENT-MAJOR order (as r5).
// ---------------------------------------------------------------------------
__global__ __launch_bounds__(256) void k0_wt(
    const float* __restrict__ w0, const float* __restrict__ w1,
    const float* __restrict__ w2, const float* __restrict__ w3,
    const float* __restrict__ w4, const float* __restrict__ w5,
    _Float16* __restrict__ wf)
{
  const float* w;
  switch (blockIdx.x) {
    case 0: w = w0; break; case 1: w = w1; break; case 2: w = w2; break;
    case 3: w = w3; break; case 4: w = w4; break; default: w = w5; break;
  }
  _Float16* out = wf + blockIdx.x * 16384;
  const int t = threadIdx.x;
  for (int it = 0; it < 64; ++it) {
    int f = it * 256 + t;
    int j  = f & 7;
    int ln = (f >> 3) & 63;
    int nt = (f >> 9) & 7;
    int k0 = f >> 12;
    int k = k0 * 32 + (ln >> 4) * 8 + j;
    int n = nt * 16 + (ln & 15);
    out[f] = (_Float16)w[k * 128 + n];
  }
}

// ---------------------------------------------------------------------------
// k2: r11 schedule (double-buffered weight prefetch, (256,3), 80 VGPR,
// 74.9us). r14: bounce stores are REGULAR (was NT since r9). All three
// outputs are re-read downstream (at/bt by k3 THREE times, gate by k4);
// NT streamed them past L2/L3 and made k3's loads cold-HBM. With the
// healthy prefetch schedule, writes are exact (110.6MB) either way.
// ---------------------------------------------------------------------------
__global__ __launch_bounds__(256, 3) void k2_ln_gemm(
    const float* __restrict__ z, const float* __restrict__ ln1g, const float* __restrict__ ln1b,
    const _Float16* __restrict__ wf,
    const float* __restrict__ ba, const float* __restrict__ bga,
    const float* __restrict__ bb, const float* __restrict__ bgb,
    const float* __restrict__ bg,
    _Float16* __restrict__ at, _Float16* __restrict__ bt, _Float16* __restrict__ gate)
{
  __shared__ __align__(16) _Float16 zns[64][136];    // zn tile, padded stride
  __shared__ __align__(16) _Float16 bnc[4][32 * 72]; // per-wave store bounce
  const int t = threadIdx.x;
  const int w = t >> 6, lane = t & 63;
  const int l15 = lane & 15, quad = lane >> 4;
  const int r0 = blockIdx.x * 64;
  const int nt0 = w * 2;

  // ---- LN1 (16-lane-group reduce)
  {
    const int g = lane >> 4, h = lane & 15;
    float4 ga = *(const float4*)(ln1g + h*8);
    float4 gb = *(const float4*)(ln1g + h*8 + 4);
    float4 bba = *(const float4*)(ln1b + h*8);
    float4 bbb = *(const float4*)(ln1b + h*8 + 4);
    #pragma unroll
    for (int rr = 0; rr < 4; ++rr) {
      int row = w * 16 + rr * 4 + g;
      const float* zp = z + (size_t)(r0 + row) * NC + h * 8;
      float4 xa = *(const float4*)zp;
      float4 xb = *(const float4*)(zp + 4);
      float s = xa.x + xa.y + xa.z + xa.w + xb.x + xb.y + xb.z + xb.w;
      float q = xa.x*xa.x + xa.y*xa.y + xa.z*xa.z + xa.w*xa.w
              + xb.x*xb.x + xb.y*xb.y + xb.z*xb.z + xb.w*xb.w;
      #pragma unroll
      for (int m = 1; m < 16; m <<= 1) { s += __shfl_xor(s, m); q += __shfl_xor(q, m); }
      float mean = s * (1.f/128.f);
      float var  = q * (1.f/128.f) - mean*mean;
      float rs = rsqrtf(var + 1e-5f);
      union { uint4 u; _Float16 hh[8]; } pk;
      pk.hh[0] = (_Float16)((xa.x - mean) * rs * ga.x + bba.x);
      pk.hh[1] = (_Float16)((xa.y - mean) * rs * ga.y + bba.y);
      pk.hh[2] = (_Float16)((xa.z - mean) * rs * ga.z + bba.z);
      pk.hh[3] = (_Float16)((xa.w - mean) * rs * ga.w + bba.w);
      pk.hh[4] = (_Float16)((xb.x - mean) * rs * gb.x + bbb.x);
      pk.hh[5] = (_Float16)((xb.y - mean) * rs * gb.y + bbb.y);
      pk.hh[6] = (_Float16)((xb.z - mean) * rs * gb.z + bbb.z);
      pk.hh[7] = (_Float16)((xb.w - mean) * rs * gb.w + bbb.w);
      *(uint4*)&zns[row][h * 8] = pk.u;
    }
  }
  __syncthreads();

  const _Float16* pw = wf + lane * 8;
  f16x8 bwA[4][2], bwB[4][2];       // double-buffered weights
  floatx4 acc[4][2];
  union PkU { unsigned int u; _Float16 h[2]; };
  PkU sig[4][2][2];

  auto loadw = [&](f16x8 (&bw)[4][2], int slot) {
    const _Float16* p = pw + slot * 16384;
    #pragma unroll
    for (int k0 = 0; k0 < 4; ++k0)
      #pragma unroll
      for (int j = 0; j < 2; ++j)
        bw[k0][j] = *(const f16x8*)(p + (k0*8 + nt0 + j) * 512);
  };
  auto dogemm = [&](const f16x8 (&bw)[4][2]) {
    #pragma unroll
    for (int mt = 0; mt < 4; ++mt) {
      acc[mt][0] = zero4(); acc[mt][1] = zero4();
      #pragma unroll
      for (int k0 = 0; k0 < 4; ++k0) {
        f16x8 af = *(const f16x8*)&zns[mt*16 + l15][k0*32 + quad*8];
        acc[mt][0] = __builtin_amdgcn_mfma_f32_16x16x32_f16(af, bw[k0][0], acc[mt][0], 0, 0, 0);
        acc[mt][1] = __builtin_amdgcn_mfma_f32_16x16x32_f16(af, bw[k0][1], acc[mt][1], 0, 0, 0);
      }
    }
  };
  auto sigpack = [&](const float* big) {
    #pragma unroll
    for (int j = 0; j < 2; ++j) {
      float bgv = big[(nt0 + j)*16 + l15];
      #pragma unroll
      for (int mt = 0; mt < 4; ++mt) {
        sig[mt][j][0].h[0] = (_Float16)sigmoidf_(acc[mt][j][0] + bgv);
        sig[mt][j][0].h[1] = (_Float16)sigmoidf_(acc[mt][j][1] + bgv);
        sig[mt][j][1].h[0] = (_Float16)sigmoidf_(acc[mt][j][2] + bgv);
        sig[mt][j][1].h[1] = (_Float16)sigmoidf_(acc[mt][j][3] + bgv);
      }
    }
  };
  auto bounce_out = [&](_Float16* dst) {
    asm volatile("s_waitcnt lgkmcnt(0)" ::: "memory");
    _Float16* base = dst + (size_t)blockIdx.x * 8192 + w * 2048;
    #pragma unroll
    for (int i = 0; i < 4; ++i) {
      int f = i * 512 + lane * 8;
      int cp = f >> 6, pos = f & 63;
      u32x4 v = *(const u32x4*)&bnc[w][cp * 72 + pos];
      *(u32x4*)(base + f) = v;        // REGULAR store: keep L2/L3-resident
    }
  };
  auto combine_store = [&](const float* bia, _Float16* dst) {
    #pragma unroll
    for (int j = 0; j < 2; ++j) {
      int c = (nt0 + j)*16 + l15;
      float bav = bia[c];
      #pragma unroll
      for (int mt = 0; mt < 4; ++mt) {
        union { uint2 u2; _Float16 h[4]; } pk;
        pk.h[0] = (_Float16)((acc[mt][j][0] + bav) * (float)sig[mt][j][0].h[0]);
        pk.h[1] = (_Float16)((acc[mt][j][1] + bav) * (float)sig[mt][j][0].h[1]);
        pk.h[2] = (_Float16)((acc[mt][j][2] + bav) * (float)sig[mt][j][1].h[0]);
        pk.h[3] = (_Float16)((acc[mt][j][3] + bav) * (float)sig[mt][j][1].h[1]);
        *(uint2*)&bnc[w][(j*16 + l15) * 72 + mt*16 + quad*4] = pk.u2;
      }
    }
    bounce_out(dst);
  };

  // schedule: every loadw >=1 GEMM ahead of its consumer
  loadw(bwA, 1); loadw(bwB, 0);      // Wga, Wa in flight together
  dogemm(bwA); sigpack(bga);         // Wga
  loadw(bwA, 3);                     // Wgb (consumed 2 phases later)
  dogemm(bwB); combine_store(ba, at);// Wa
  loadw(bwB, 2);                     // Wb
  dogemm(bwA); sigpack(bgb);         // Wgb
  loadw(bwA, 4);                     // Wg
  dogemm(bwB); combine_store(bb, bt);// Wb
  dogemm(bwA);                       // Wg
  #pragma unroll
  for (int j = 0; j < 2; ++j) {
    float bgv = bg[(nt0 + j)*16 + l15];
    #pragma unroll
    for (int mt = 0; mt < 4; ++mt) {
      union { uint2 u2; _Float16 h[4]; } pk;
      #pragma unroll
      for (int r = 0; r < 4; ++r)
        pk.h[r] = (_Float16)sigmoidf_(acc[mt][j][r] + bgv);
      *(uint2*)&bnc[w][(j*16 + l15) * 72 + mt*16 + quad*4] = pk.u2;
    }
  }
  bounce_out(gate);
}

// ---------------------------------------------------------------------------
// k3: r8-structure (256 thr, 4 waves of 64x64, K-step 32, P/Q staging, one
// barrier per step, stride-40 LDS). o16 stored with REGULAR stores (re-read
// by k4). (unchanged from r13)
// ---------------------------------------------------------------------------
__global__ __launch_bounds__(256, 3) void k3_tri(
    const _Float16* __restrict__ at, const _Float16* __restrict__ bt, _Float16* __restrict__ o)
{
  __shared__ __align__(16) _Float16 As[2][128 * 40];
  __shared__ __align__(16) _Float16 Bs[2][128 * 40];
  const int t = threadIdx.x;
  const int w = t >> 6, lane = t & 63, l15 = lane & 15, quad = lane >> 4;
  const int c = blockIdx.y;
  const int i0 = (blockIdx.x / 3) * 128, j0 = (blockIdx.x % 3) * 128;
  const int wi = w >> 1, wj = w & 1;

  // staging: row = t>>1 (0..127), half = (t&1)*16 fp16 (32B); 64B/row/step
  const int srow = t >> 1, sch = (t & 1) * 16;
  const _Float16* gaRow = at + (size_t)(i0 + srow) * 6 * 8192 + (size_t)c * 64;
  const _Float16* gbRow = bt + (size_t)(j0 + srow) * 6 * 8192 + (size_t)c * 64;
  _Float16* const pa0 = &As[0][srow * 40 + sch];
  _Float16* const pb0 = &Bs[0][srow * 40 + sch];
  _Float16* const pa1 = &As[1][srow * 40 + sch];
  _Float16* const pb1 = &Bs[1][srow * 40 + sch];

  floatx4 acc[4][4];
  #pragma unroll
  for (int mt = 0; mt < 4; ++mt)
    #pragma unroll
    for (int nt = 0; nt < 4; ++nt) acc[mt][nt] = zero4();

  f16x8 aP0,aP1,bP0,bP1, aQ0,aQ1,bQ0,bQ1;

  auto gofs = [&](int kk) -> size_t {
    int x = kk + sch;                       // within-row k offset
    return (size_t)(x >> 6) * 8192 + (size_t)(x & 63);
  };
  auto gloadP = [&](int kk) {
    size_t go = gofs(kk);
    aP0 = *(const f16x8*)(gaRow + go); aP1 = *(const f16x8*)(gaRow + go + 8);
    bP0 = *(const f16x8*)(gbRow + go); bP1 = *(const f16x8*)(gbRow + go + 8);
  };
  auto gloadQ = [&](int kk) {
    size_t go = gofs(kk);
    aQ0 = *(const f16x8*)(gaRow + go); aQ1 = *(const f16x8*)(gaRow + go + 8);
    bQ0 = *(const f16x8*)(gbRow + go); bQ1 = *(const f16x8*)(gbRow + go + 8);
  };
  auto swriteP = [&](int buf) {
    _Float16* pa = buf ? pa1 : pa0; _Float16* pb = buf ? pb1 : pb0;
    *(f16x8*)pa = aP0; *(f16x8*)(pa + 8) = aP1;
    *(f16x8*)pb = bP0; *(f16x8*)(pb + 8) = bP1;
  };
  auto swriteQ = [&](int buf) {
    _Float16* pa = buf ? pa1 : pa0; _Float16* pb = buf ? pb1 : pb0;
    *(f16x8*)pa = aQ0; *(f16x8*)(pa + 8) = aQ1;
    *(f16x8*)pb = bQ0; *(f16x8*)(pb + 8) = bQ1;
  };
  auto compute = [&](int buf) {
    f16x8 af[4], bfr[4];
    #pragma unroll
    for (int mt = 0; mt < 4; ++mt)
      af[mt] = *(const f16x8*)&As[buf][(wi*64 + mt*16 + l15) * 40 + quad*8];
    #pragma unroll
    for (int nt = 0; nt < 4; ++nt)
      bfr[nt] = *(const f16x8*)&Bs[buf][(wj*64 + nt*16 + l15) * 40 + quad*8];
    #pragma unroll
    for (int mt = 0; mt < 4; ++mt)
      #pragma unroll
      for (int nt = 0; nt < 4; ++nt)
        acc[mt][nt] = __builtin_amdgcn_mfma_f32_16x16x32_f16(af[mt], bfr[nt], acc[mt][nt], 0, 0, 0);
  };

  // 12 K-steps of 32. step s lives in buf[s&1].
  gloadP(0); swriteP(0); gloadP(32);
  __syncthreads();
  #pragma unroll
  for (int s = 0; s < 12; s += 2) {
    if (s + 2 < 12) gloadQ((s + 2) * 32);   // in flight during compute
    compute(0);
    swriteP(1);                              // step s+1 -> buf1
    __syncthreads();
    if (s + 3 < 12) gloadP((s + 3) * 32);
    compute(1);
    if (s + 2 < 12) { swriteQ(0); __syncthreads(); }
  }

  // store o16 in chunk layout, REGULAR stores (keep L2/L3-resident for k4)
  #pragma unroll
  for (int mt = 0; mt < 4; ++mt) {
    #pragma unroll
    for (int r = 0; r < 4; ++r) {
      int i = i0 + wi*64 + mt*16 + quad*4 + r;
      _Float16* obase = o + (size_t)(i*6 + (j0 >> 6) + wj) * 8192 + (size_t)c * 64;
      #pragma unroll
      for (int nt = 0; nt < 4; ++nt)
        obase[nt*16 + l15] = (_Float16)acc[mt][nt][r];
    }
  }
}

// ---------------------------------------------------------------------------
// k4: Wo-fragment and gate loads hoisted to the TOP (independent of the o16
// pipeline) so the post-LN2 tail has zero cold loads. NT only on `out`
// (never re-read). (unchanged from r13)
// ---------------------------------------------------------------------------
__global__ __launch_bounds__(256, 4) void k4_out(
    const _Float16* __restrict__ o, const _Float16* __restrict__ gate,
    const float* __restrict__ ln2g, const float* __restrict__ ln2b,
    const _Float16* __restrict__ wo5, const float* __restrict__ bo,
    float* __restrict__ out)
{
  __shared__ __align__(16) _Float16 osb[64][136];
  const int t = threadIdx.x;
  const int w = t >> 6, lane = t & 63, l15 = lane & 15, quad = lane >> 4;
  const int r0 = blockIdx.x * 64;
  const int nt0 = w * 2;

  // hoisted: weights + gate (both independent of o16)
  f16x8 bw[4][2];
  {
    const _Float16* p = wo5 + lane * 8;
    #pragma unroll
    for (int k0 = 0; k0 < 4; ++k0)
      #pragma unroll
      for (int j = 0; j < 2; ++j)
        bw[k0][j] = *(const f16x8*)(p + (k0*8 + nt0 + j) * 512);
  }
  union GkU { uint2 u2; _Float16 h[4]; };
  GkU gk[2][4];
  #pragma unroll
  for (int j = 0; j < 2; ++j) {
    int cch = (nt0 + j)*16 + l15;
    #pragma unroll
    for (int mt = 0; mt < 4; ++mt)
      gk[j][mt].u2 = *(const uint2*)(gate + (size_t)blockIdx.x * 8192 + (size_t)cch * 64 + mt*16 + quad*4);
  }

  // gather o16 chunk -> LDS transpose
  {
    const _Float16* ob = o + (size_t)blockIdx.x * 8192;
    #pragma unroll
    for (int it = 0; it < 4; ++it) {
      int f = (it * 256 + t) * 8;
      int cx = f >> 6, p = f & 63;
      f16x8 v = *(const f16x8*)(ob + f);
      #pragma unroll
      for (int i = 0; i < 8; ++i) osb[p + i][cx] = v[i];
    }
  }
  __syncthreads();

  // LN2 in place
  {
    const int g = lane >> 4, h = lane & 15;
    float4 ga = *(const float4*)(ln2g + h*8);
    float4 gb = *(const float4*)(ln2g + h*8 + 4);
    float4 bba = *(const float4*)(ln2b + h*8);
    float4 bbb = *(const float4*)(ln2b + h*8 + 4);
    #pragma unroll
    for (int rr = 0; rr < 4; ++rr) {
      int row = w * 16 + rr * 4 + g;
      f16x8 xv = *(const f16x8*)&osb[row][h*8];
      float x0 = (float)xv[0], x1 = (float)xv[1], x2 = (float)xv[2], x3 = (float)xv[3];
      float x4 = (float)xv[4], x5 = (float)xv[5], x6 = (float)xv[6], x7 = (float)xv[7];
      float s = x0+x1+x2+x3+x4+x5+x6+x7;
      float q = x0*x0+x1*x1+x2*x2+x3*x3+x4*x4+x5*x5+x6*x6+x7*x7;
      #pragma unroll
      for (int m = 1; m < 16; m <<= 1) { s += __shfl_xor(s, m); q += __shfl_xor(q, m); }
      float mean = s * (1.f/128.f);
      float var  = q * (1.f/128.f) - mean*mean;
      float rs = rsqrtf(var + 1e-5f);
      union { uint4 u; _Float16 hh[8]; } pk;
      pk.hh[0] = (_Float16)((x0 - mean) * rs * ga.x + bba.x);
      pk.hh[1] = (_Float16)((x1 - mean) * rs * ga.y + bba.y);
      pk.hh[2] = (_Float16)((x2 - mean) * rs * ga.z + bba.z);
      pk.hh[3] = (_Float16)((x3 - mean) * rs * ga.w + bba.w);
      pk.hh[4] = (_Float16)((x4 - mean) * rs * gb.x + bbb.x);
      pk.hh[5] = (_Float16)((x5 - mean) * rs * gb.y + bbb.y);
      pk.hh[6] = (_Float16)((x6 - mean) * rs * gb.z + bbb.z);
      pk.hh[7] = (_Float16)((x7 - mean) * rs * gb.w + bbb.w);
      *(uint4*)&osb[row][h * 8] = pk.u;
    }
  }
  __syncthreads();

  floatx4 acc[4][2];
  #pragma unroll
  for (int mt = 0; mt < 4; ++mt) {
    acc[mt][0] = zero4(); acc[mt][1] = zero4();
    #pragma unroll
    for (int k0 = 0; k0 < 4; ++k0) {
      f16x8 af = *(const f16x8*)&osb[mt*16 + l15][k0*32 + quad*8];
      acc[mt][0] = __builtin_amdgcn_mfma_f32_16x16x32_f16(af, bw[k0][0], acc[mt][0], 0, 0, 0);
      acc[mt][1] = __builtin_amdgcn_mfma_f32_16x16x32_f16(af, bw[k0][1], acc[mt][1], 0, 0, 0);
    }
  }

  #pragma unroll
  for (int j = 0; j < 2; ++j) {
    int cch = (nt0 + j)*16 + l15;
    float bov = bo[cch];
    #pragma unroll
    for (int mt = 0; mt < 4; ++mt) {
      #pragma unroll
      for (int r = 0; r < 4; ++r) {
        int rl = mt*16 + quad*4 + r;
        __builtin_nontemporal_store((float)gk[j][mt].h[r] * (acc[mt][j][r] + bov),
                                    out + (size_t)(r0 + rl) * NC + cch);
      }
    }
  }
}

// ---------------------------------------------------------------------------
// Workspace layout (bytes): as round 8 (all chunk-layout fp16 + wf).
// ---------------------------------------------------------------------------
extern "C" void kernel_launch(void* const* d_in, const int* in_sizes, int n_in,
                              void* d_out, int out_size, void* d_ws, size_t ws_size,
                              hipStream_t stream) {
  const float* z    = (const float*)d_in[0];
  const float* l1g  = (const float*)d_in[1];
  const float* l1b  = (const float*)d_in[2];
  const float* l2g  = (const float*)d_in[3];
  const float* l2b  = (const float*)d_in[4];
  const float* Wa   = (const float*)d_in[5];
  const float* ba   = (const float*)d_in[6];
  const float* Wga  = (const float*)d_in[7];
  const float* bga  = (const float*)d_in[8];
  const float* Wb   = (const float*)d_in[9];
  const float* bb   = (const float*)d_in[10];
  const float* Wgb  = (const float*)d_in[11];
  const float* bgb  = (const float*)d_in[12];
  const float* Wg   = (const float*)d_in[13];
  const float* bg   = (const float*)d_in[14];
  const float* Wo   = (const float*)d_in[15];
  const float* bo   = (const float*)d_in[16];

  char* ws = (char*)d_ws;
  _Float16* at_  = (_Float16*)(ws + 0);
  _Float16* bt_  = (_Float16*)(ws + 37748736);
  _Float16* gate = (_Float16*)(ws + 75497472);
  _Float16* o16  = (_Float16*)(ws + 113246208);
  _Float16* wf   = (_Float16*)(ws + 188743680);

  hipLaunchKernelGGL(k0_wt, dim3(6), dim3(256), 0, stream, Wa, Wga, Wb, Wgb, Wg, Wo, wf);
  hipLaunchKernelGGL(k2_ln_gemm, dim3(2304), dim3(256), 0, stream,
                     z, l1g, l1b, wf, ba, bga, bb, bgb, bg, at_, bt_, gate);
  hipLaunchKernelGGL(k3_tri, dim3(9, 128), dim3(256), 0, stream, at_, bt_, o16);
  hipLaunchKernelGGL(k4_out, dim3(2304), dim3(256), 0, stream,
                     o16, gate, l2g, l2b, wf + 5*16384, bo, (float*)d_out);
}

// Round 16
// 274.791 us; speedup vs baseline: 1.2473x; 1.0193x over previous
//
#include <hip/hip_runtime.h>
#include <stdint.h>

typedef _Float16 f16x8 __attribute__((ext_vector_type(8)));
typedef float floatx4 __attribute__((ext_vector_type(4)));
typedef unsigned int u32x4 __attribute__((ext_vector_type(4)));

#define RR 147456   // 384*384 rows
#define NC 128      // channels
#define NN 384
// chunk-interleaved layout for at/bt/gate/o16:
//   addr(pos, c) = (pos>>6)*8192 + c*64 + (pos&63)   [fp16 units]

__device__ inline floatx4 zero4() { floatx4 v; v[0]=0.f; v[1]=0.f; v[2]=0.f; v[3]=0.f; return v; }
__device__ inline float sigmoidf_(float x) { return 1.f / (1.f + __expf(-x)); }

// ---------------------------------------------------------------------------
// k0: repack six fp32 128x128 weights into fp16 FRAGMENT-MAJOR order (as r5).
// ---------------------------------------------------------------------------
__global__ __launch_bounds__(256) void k0_wt(
    const float* __restrict__ w0, const float* __restrict__ w1,
    const float* __restrict__ w2, const float* __restrict__ w3,
    const float* __restrict__ w4, const float* __restrict__ w5,
    _Float16* __restrict__ wf)
{
  const float* w;
  switch (blockIdx.x) {
    case 0: w = w0; break; case 1: w = w1; break; case 2: w = w2; break;
    case 3: w = w3; break; case 4: w = w4; break; default: w = w5; break;
  }
  _Float16* out = wf + blockIdx.x * 16384;
  const int t = threadIdx.x;
  for (int it = 0; it < 64; ++it) {
    int f = it * 256 + t;
    int j  = f & 7;
    int ln = (f >> 3) & 63;
    int nt = (f >> 9) & 7;
    int k0 = f >> 12;
    int k = k0 * 32 + (ln >> 4) * 8 + j;
    int n = nt * 16 + (ln & 15);
    out[f] = (_Float16)w[k * 128 + n];
  }
}

// ---------------------------------------------------------------------------
// k2: FROZEN at r14 config (78us): r11 double-buffered weight prefetch,
// (256,3), 80 VGPR, regular bounce stores (outputs L2/L3-resident for k3/k4).
// ---------------------------------------------------------------------------
__global__ __launch_bounds__(256, 3) void k2_ln_gemm(
    const float* __restrict__ z, const float* __restrict__ ln1g, const float* __restrict__ ln1b,
    const _Float16* __restrict__ wf,
    const float* __restrict__ ba, const float* __restrict__ bga,
    const float* __restrict__ bb, const float* __restrict__ bgb,
    const float* __restrict__ bg,
    _Float16* __restrict__ at, _Float16* __restrict__ bt, _Float16* __restrict__ gate)
{
  __shared__ __align__(16) _Float16 zns[64][136];    // zn tile, padded stride
  __shared__ __align__(16) _Float16 bnc[4][32 * 72]; // per-wave store bounce
  const int t = threadIdx.x;
  const int w = t >> 6, lane = t & 63;
  const int l15 = lane & 15, quad = lane >> 4;
  const int r0 = blockIdx.x * 64;
  const int nt0 = w * 2;

  // ---- LN1 (16-lane-group reduce)
  {
    const int g = lane >> 4, h = lane & 15;
    float4 ga = *(const float4*)(ln1g + h*8);
    float4 gb = *(const float4*)(ln1g + h*8 + 4);
    float4 bba = *(const float4*)(ln1b + h*8);
    float4 bbb = *(const float4*)(ln1b + h*8 + 4);
    #pragma unroll
    for (int rr = 0; rr < 4; ++rr) {
      int row = w * 16 + rr * 4 + g;
      const float* zp = z + (size_t)(r0 + row) * NC + h * 8;
      float4 xa = *(const float4*)zp;
      float4 xb = *(const float4*)(zp + 4);
      float s = xa.x + xa.y + xa.z + xa.w + xb.x + xb.y + xb.z + xb.w;
      float q = xa.x*xa.x + xa.y*xa.y + xa.z*xa.z + xa.w*xa.w
              + xb.x*xb.x + xb.y*xb.y + xb.z*xb.z + xb.w*xb.w;
      #pragma unroll
      for (int m = 1; m < 16; m <<= 1) { s += __shfl_xor(s, m); q += __shfl_xor(q, m); }
      float mean = s * (1.f/128.f);
      float var  = q * (1.f/128.f) - mean*mean;
      float rs = rsqrtf(var + 1e-5f);
      union { uint4 u; _Float16 hh[8]; } pk;
      pk.hh[0] = (_Float16)((xa.x - mean) * rs * ga.x + bba.x);
      pk.hh[1] = (_Float16)((xa.y - mean) * rs * ga.y + bba.y);
      pk.hh[2] = (_Float16)((xa.z - mean) * rs * ga.z + bba.z);
      pk.hh[3] = (_Float16)((xa.w - mean) * rs * ga.w + bba.w);
      pk.hh[4] = (_Float16)((xb.x - mean) * rs * gb.x + bbb.x);
      pk.hh[5] = (_Float16)((xb.y - mean) * rs * gb.y + bbb.y);
      pk.hh[6] = (_Float16)((xb.z - mean) * rs * gb.z + bbb.z);
      pk.hh[7] = (_Float16)((xb.w - mean) * rs * gb.w + bbb.w);
      *(uint4*)&zns[row][h * 8] = pk.u;
    }
  }
  __syncthreads();

  const _Float16* pw = wf + lane * 8;
  f16x8 bwA[4][2], bwB[4][2];       // double-buffered weights
  floatx4 acc[4][2];
  union PkU { unsigned int u; _Float16 h[2]; };
  PkU sig[4][2][2];

  auto loadw = [&](f16x8 (&bw)[4][2], int slot) {
    const _Float16* p = pw + slot * 16384;
    #pragma unroll
    for (int k0 = 0; k0 < 4; ++k0)
      #pragma unroll
      for (int j = 0; j < 2; ++j)
        bw[k0][j] = *(const f16x8*)(p + (k0*8 + nt0 + j) * 512);
  };
  auto dogemm = [&](const f16x8 (&bw)[4][2]) {
    #pragma unroll
    for (int mt = 0; mt < 4; ++mt) {
      acc[mt][0] = zero4(); acc[mt][1] = zero4();
      #pragma unroll
      for (int k0 = 0; k0 < 4; ++k0) {
        f16x8 af = *(const f16x8*)&zns[mt*16 + l15][k0*32 + quad*8];
        acc[mt][0] = __builtin_amdgcn_mfma_f32_16x16x32_f16(af, bw[k0][0], acc[mt][0], 0, 0, 0);
        acc[mt][1] = __builtin_amdgcn_mfma_f32_16x16x32_f16(af, bw[k0][1], acc[mt][1], 0, 0, 0);
      }
    }
  };
  auto sigpack = [&](const float* big) {
    #pragma unroll
    for (int j = 0; j < 2; ++j) {
      float bgv = big[(nt0 + j)*16 + l15];
      #pragma unroll
      for (int mt = 0; mt < 4; ++mt) {
        sig[mt][j][0].h[0] = (_Float16)sigmoidf_(acc[mt][j][0] + bgv);
        sig[mt][j][0].h[1] = (_Float16)sigmoidf_(acc[mt][j][1] + bgv);
        sig[mt][j][1].h[0] = (_Float16)sigmoidf_(acc[mt][j][2] + bgv);
        sig[mt][j][1].h[1] = (_Float16)sigmoidf_(acc[mt][j][3] + bgv);
      }
    }
  };
  auto bounce_out = [&](_Float16* dst) {
    asm volatile("s_waitcnt lgkmcnt(0)" ::: "memory");
    _Float16* base = dst + (size_t)blockIdx.x * 8192 + w * 2048;
    #pragma unroll
    for (int i = 0; i < 4; ++i) {
      int f = i * 512 + lane * 8;
      int cp = f >> 6, pos = f & 63;
      u32x4 v = *(const u32x4*)&bnc[w][cp * 72 + pos];
      *(u32x4*)(base + f) = v;        // regular store: keep L2/L3-resident
    }
  };
  auto combine_store = [&](const float* bia, _Float16* dst) {
    #pragma unroll
    for (int j = 0; j < 2; ++j) {
      int c = (nt0 + j)*16 + l15;
      float bav = bia[c];
      #pragma unroll
      for (int mt = 0; mt < 4; ++mt) {
        union { uint2 u2; _Float16 h[4]; } pk;
        pk.h[0] = (_Float16)((acc[mt][j][0] + bav) * (float)sig[mt][j][0].h[0]);
        pk.h[1] = (_Float16)((acc[mt][j][1] + bav) * (float)sig[mt][j][0].h[1]);
        pk.h[2] = (_Float16)((acc[mt][j][2] + bav) * (float)sig[mt][j][1].h[0]);
        pk.h[3] = (_Float16)((acc[mt][j][3] + bav) * (float)sig[mt][j][1].h[1]);
        *(uint2*)&bnc[w][(j*16 + l15) * 72 + mt*16 + quad*4] = pk.u2;
      }
    }
    bounce_out(dst);
  };

  // schedule: every loadw >=1 GEMM ahead of its consumer
  loadw(bwA, 1); loadw(bwB, 0);      // Wga, Wa in flight together
  dogemm(bwA); sigpack(bga);         // Wga
  loadw(bwA, 3);                     // Wgb (consumed 2 phases later)
  dogemm(bwB); combine_store(ba, at);// Wa
  loadw(bwB, 2);                     // Wb
  dogemm(bwA); sigpack(bgb);         // Wgb
  loadw(bwA, 4);                     // Wg
  dogemm(bwB); combine_store(bb, bt);// Wb
  dogemm(bwA);                       // Wg
  #pragma unroll
  for (int j = 0; j < 2; ++j) {
    float bgv = bg[(nt0 + j)*16 + l15];
    #pragma unroll
    for (int mt = 0; mt < 4; ++mt) {
      union { uint2 u2; _Float16 h[4]; } pk;
      #pragma unroll
      for (int r = 0; r < 4; ++r)
        pk.h[r] = (_Float16)sigmoidf_(acc[mt][j][r] + bgv);
      *(uint2*)&bnc[w][(j*16 + l15) * 72 + mt*16 + quad*4] = pk.u2;
    }
  }
  bounce_out(gate);
}

// ---------------------------------------------------------------------------
// k3: r8-structure (256 thr, 4 waves of 64x64, K-step 32, stride-40 LDS,
// one barrier per step). NEW r16: THREE register staging sets (S0/S1/S2;
// set for step s = s%3, LDS buffer = s&1), global loads issued 3 full
// compute-steps before consumption (~600-750cy coverage vs ~400 before) —
// at/bt are L3-resident (r14) but L3-hit latency (~500cy) exceeded the old
// 2-step distance. 12 steps fully unrolled, all indices compile-time.
// ---------------------------------------------------------------------------
__global__ __launch_bounds__(256, 3) void k3_tri(
    const _Float16* __restrict__ at, const _Float16* __restrict__ bt, _Float16* __restrict__ o)
{
  __shared__ __align__(16) _Float16 As[2][128 * 40];
  __shared__ __align__(16) _Float16 Bs[2][128 * 40];
  const int t = threadIdx.x;
  const int w = t >> 6, lane = t & 63, l15 = lane & 15, quad = lane >> 4;
  const int c = blockIdx.y;
  const int i0 = (blockIdx.x / 3) * 128, j0 = (blockIdx.x % 3) * 128;
  const int wi = w >> 1, wj = w & 1;

  // staging: row = t>>1 (0..127), half = (t&1)*16 fp16 (32B); 64B/row/step
  const int srow = t >> 1, sch = (t & 1) * 16;
  const _Float16* gaRow = at + (size_t)(i0 + srow) * 6 * 8192 + (size_t)c * 64;
  const _Float16* gbRow = bt + (size_t)(j0 + srow) * 6 * 8192 + (size_t)c * 64;
  _Float16* const pa0 = &As[0][srow * 40 + sch];
  _Float16* const pb0 = &Bs[0][srow * 40 + sch];
  _Float16* const pa1 = &As[1][srow * 40 + sch];
  _Float16* const pb1 = &Bs[1][srow * 40 + sch];

  floatx4 acc[4][4];
  #pragma unroll
  for (int mt = 0; mt < 4; ++mt)
    #pragma unroll
    for (int nt = 0; nt < 4; ++nt) acc[mt][nt] = zero4();

  // three named staging sets (rule #20: static indexing only)
  f16x8 a00,a01,b00,b01;   // set 0
  f16x8 a10,a11,b10,b11;   // set 1
  f16x8 a20,a21,b20,b21;   // set 2

  auto gofs = [&](int kk) -> size_t {
    int x = kk + sch;
    return (size_t)(x >> 6) * 8192 + (size_t)(x & 63);
  };
  auto gload0 = [&](int kk) {
    size_t go = gofs(kk);
    a00 = *(const f16x8*)(gaRow + go); a01 = *(const f16x8*)(gaRow + go + 8);
    b00 = *(const f16x8*)(gbRow + go); b01 = *(const f16x8*)(gbRow + go + 8);
  };
  auto gload1 = [&](int kk) {
    size_t go = gofs(kk);
    a10 = *(const f16x8*)(gaRow + go); a11 = *(const f16x8*)(gaRow + go + 8);
    b10 = *(const f16x8*)(gbRow + go); b11 = *(const f16x8*)(gbRow + go + 8);
  };
  auto gload2 = [&](int kk) {
    size_t go = gofs(kk);
    a20 = *(const f16x8*)(gaRow + go); a21 = *(const f16x8*)(gaRow + go + 8);
    b20 = *(const f16x8*)(gbRow + go); b21 = *(const f16x8*)(gbRow + go + 8);
  };
  auto swrite0 = [&](int buf) {
    _Float16* pa = buf ? pa1 : pa0; _Float16* pb = buf ? pb1 : pb0;
    *(f16x8*)pa = a00; *(f16x8*)(pa + 8) = a01;
    *(f16x8*)pb = b00; *(f16x8*)(pb + 8) = b01;
  };
  auto swrite1 = [&](int buf) {
    _Float16* pa = buf ? pa1 : pa0; _Float16* pb = buf ? pb1 : pb0;
    *(f16x8*)pa = a10; *(f16x8*)(pa + 8) = a11;
    *(f16x8*)pb = b10; *(f16x8*)(pb + 8) = b11;
  };
  auto swrite2 = [&](int buf) {
    _Float16* pa = buf ? pa1 : pa0; _Float16* pb = buf ? pb1 : pb0;
    *(f16x8*)pa = a20; *(f16x8*)(pa + 8) = a21;
    *(f16x8*)pb = b20; *(f16x8*)(pb + 8) = b21;
  };
  auto compute = [&](int buf) {
    f16x8 af[4], bfr[4];
    #pragma unroll
    for (int mt = 0; mt < 4; ++mt)
      af[mt] = *(const f16x8*)&As[buf][(wi*64 + mt*16 + l15) * 40 + quad*8];
    #pragma unroll
    for (int nt = 0; nt < 4; ++nt)
      bfr[nt] = *(const f16x8*)&Bs[buf][(wj*64 + nt*16 + l15) * 40 + quad*8];
    #pragma unroll
    for (int mt = 0; mt < 4; ++mt)
      #pragma unroll
      for (int nt = 0; nt < 4; ++nt)
        acc[mt][nt] = __builtin_amdgcn_mfma_f32_16x16x32_f16(af[mt], bfr[nt], acc[mt][nt], 0, 0, 0);
  };

  // prologue: steps 0,1,2 in sets; steps 0,1 into LDS; refill sets 0,1
  gload0(0); gload1(32); gload2(64);
  swrite0(0); swrite1(1);
  gload0(96); gload1(128);
  __syncthreads();
  // 12 steps, one barrier each; swrite(s+2) AFTER barrier(s); gload(s+5)
  compute(0); __syncthreads(); swrite2(0); gload2(160);   // s=0
  compute(1); __syncthreads(); swrite0(1); gload0(192);   // s=1
  compute(0); __syncthreads(); swrite1(0); gload1(224);   // s=2
  compute(1); __syncthreads(); swrite2(1); gload2(256);   // s=3
  compute(0); __syncthreads(); swrite0(0); gload0(288);   // s=4
  compute(1); __syncthreads(); swrite1(1); gload1(320);   // s=5
  compute(0); __syncthreads(); swrite2(0); gload2(352);   // s=6
  compute(1); __syncthreads(); swrite0(1);                // s=7
  compute(0); __syncthreads(); swrite1(0);                // s=8
  compute(1); __syncthreads(); swrite2(1);                // s=9
  compute(0); __syncthreads();                            // s=10
  compute(1);                                             // s=11

  // store o16 in chunk layout, REGULAR stores (keep L2/L3-resident for k4)
  #pragma unroll
  for (int mt = 0; mt < 4; ++mt) {
    #pragma unroll
    for (int r = 0; r < 4; ++r) {
      int i = i0 + wi*64 + mt*16 + quad*4 + r;
      _Float16* obase = o + (size_t)(i*6 + (j0 >> 6) + wj) * 8192 + (size_t)c * 64;
      #pragma unroll
      for (int nt = 0; nt < 4; ++nt)
        obase[nt*16 + l15] = (_Float16)acc[mt][nt][r];
    }
  }
}

// ---------------------------------------------------------------------------
// k4: NEW r16: XOR-swizzled osb. The o16->LDS transpose was an 8-way bank
// conflict (8 lanes share a channel and write rows p=0,8..56 at stride
// 136 fp16: 8*272B = 0 mod 128 -> same bank). Swizzle the 16B column group
// by (row>>3) at ALL osb access sites (gather-write / LN2 / af read):
// 8 lanes now hit 8 distinct banks. Rows stay 16B-aligned.
// ---------------------------------------------------------------------------
__global__ __launch_bounds__(256, 4) void k4_out(
    const _Float16* __restrict__ o, const _Float16* __restrict__ gate,
    const float* __restrict__ ln2g, const float* __restrict__ ln2b,
    const _Float16* __restrict__ wo5, const float* __restrict__ bo,
    float* __restrict__ out)
{
  __shared__ __align__(16) _Float16 osb[64][136];
  const int t = threadIdx.x;
  const int w = t >> 6, lane = t & 63, l15 = lane & 15, quad = lane >> 4;
  const int r0 = blockIdx.x * 64;
  const int nt0 = w * 2;

  // hoisted: weights + gate (both independent of o16)
  f16x8 bw[4][2];
  {
    const _Float16* p = wo5 + lane * 8;
    #pragma unroll
    for (int k0 = 0; k0 < 4; ++k0)
      #pragma unroll
      for (int j = 0; j < 2; ++j)
        bw[k0][j] = *(const f16x8*)(p + (k0*8 + nt0 + j) * 512);
  }
  union GkU { uint2 u2; _Float16 h[4]; };
  GkU gk[2][4];
  #pragma unroll
  for (int j = 0; j < 2; ++j) {
    int cch = (nt0 + j)*16 + l15;
    #pragma unroll
    for (int mt = 0; mt < 4; ++mt)
      gk[j][mt].u2 = *(const uint2*)(gate + (size_t)blockIdx.x * 8192 + (size_t)cch * 64 + mt*16 + quad*4);
  }

  // gather o16 chunk -> LDS transpose with column-group swizzle
  {
    const _Float16* ob = o + (size_t)blockIdx.x * 8192;
    #pragma unroll
    for (int it = 0; it < 4; ++it) {
      int f = (it * 256 + t) * 8;
      int cx = f >> 6, p = f & 63;          // channel, pos base (mult of 8)
      f16x8 v = *(const f16x8*)(ob + f);
      int cxg = cx >> 3, cl = cx & 7;
      int rg = p >> 3;                       // (p+i)>>3 == p>>3 for i<8
      int col = ((cxg ^ rg) << 3) | cl;
      #pragma unroll
      for (int i = 0; i < 8; ++i) osb[p + i][col] = v[i];
    }
  }
  __syncthreads();

  // LN2 in place (swizzled column group h ^ (row>>3))
  {
    const int g = lane >> 4, h = lane & 15;
    float4 ga = *(const float4*)(ln2g + h*8);
    float4 gb = *(const float4*)(ln2g + h*8 + 4);
    float4 bba = *(const float4*)(ln2b + h*8);
    float4 bbb = *(const float4*)(ln2b + h*8 + 4);
    #pragma unroll
    for (int rr = 0; rr < 4; ++rr) {
      int row = w * 16 + rr * 4 + g;
      int col = ((h ^ (row >> 3)) << 3);
      f16x8 xv = *(const f16x8*)&osb[row][col];
      float x0 = (float)xv[0], x1 = (float)xv[1], x2 = (float)xv[2], x3 = (float)xv[3];
      float x4 = (float)xv[4], x5 = (float)xv[5], x6 = (float)xv[6], x7 = (float)xv[7];
      float s = x0+x1+x2+x3+x4+x5+x6+x7;
      float q = x0*x0+x1*x1+x2*x2+x3*x3+x4*x4+x5*x5+x6*x6+x7*x7;
      #pragma unroll
      for (int m = 1; m < 16; m <<= 1) { s += __shfl_xor(s, m); q += __shfl_xor(q, m); }
      float mean = s * (1.f/128.f);
      float var  = q * (1.f/128.f) - mean*mean;
      float rs = rsqrtf(var + 1e-5f);
      union { uint4 u; _Float16 hh[8]; } pk;
      pk.hh[0] = (_Float16)((x0 - mean) * rs * ga.x + bba.x);
      pk.hh[1] = (_Float16)((x1 - mean) * rs * ga.y + bba.y);
      pk.hh[2] = (_Float16)((x2 - mean) * rs * ga.z + bba.z);
      pk.hh[3] = (_Float16)((x3 - mean) * rs * ga.w + bba.w);
      pk.hh[4] = (_Float16)((x4 - mean) * rs * gb.x + bbb.x);
      pk.hh[5] = (_Float16)((x5 - mean) * rs * gb.y + bbb.y);
      pk.hh[6] = (_Float16)((x6 - mean) * rs * gb.z + bbb.z);
      pk.hh[7] = (_Float16)((x7 - mean) * rs * gb.w + bbb.w);
      *(uint4*)&osb[row][col] = pk.u;
    }
  }
  __syncthreads();

  floatx4 acc[4][2];
  #pragma unroll
  for (int mt = 0; mt < 4; ++mt) {
    acc[mt][0] = zero4(); acc[mt][1] = zero4();
    #pragma unroll
    for (int k0 = 0; k0 < 4; ++k0) {
      int row = mt*16 + l15;
      int col = (((k0*4 + quad) ^ (row >> 3)) << 3);
      f16x8 af = *(const f16x8*)&osb[row][col];
      acc[mt][0] = __builtin_amdgcn_mfma_f32_16x16x32_f16(af, bw[k0][0], acc[mt][0], 0, 0, 0);
      acc[mt][1] = __builtin_amdgcn_mfma_f32_16x16x32_f16(af, bw[k0][1], acc[mt][1], 0, 0, 0);
    }
  }

  #pragma unroll
  for (int j = 0; j < 2; ++j) {
    int cch = (nt0 + j)*16 + l15;
    float bov = bo[cch];
    #pragma unroll
    for (int mt = 0; mt < 4; ++mt) {
      #pragma unroll
      for (int r = 0; r < 4; ++r) {
        int rl = mt*16 + quad*4 + r;
        __builtin_nontemporal_store((float)gk[j][mt].h[r] * (acc[mt][j][r] + bov),
                                    out + (size_t)(r0 + rl) * NC + cch);
      }
    }
  }
}

// ---------------------------------------------------------------------------
// Workspace layout (bytes): as round 8 (all chunk-layout fp16 + wf).
// ---------------------------------------------------------------------------
extern "C" void kernel_launch(void* const* d_in, const int* in_sizes, int n_in,
                              void* d_out, int out_size, void* d_ws, size_t ws_size,
                              hipStream_t stream) {
  const float* z    = (const float*)d_in[0];
  const float* l1g  = (const float*)d_in[1];
  const float* l1b  = (const float*)d_in[2];
  const float* l2g  = (const float*)d_in[3];
  const float* l2b  = (const float*)d_in[4];
  const float* Wa   = (const float*)d_in[5];
  const float* ba   = (const float*)d_in[6];
  const float* Wga  = (const float*)d_in[7];
  const float* bga  = (const float*)d_in[8];
  const float* Wb   = (const float*)d_in[9];
  const float* bb   = (const float*)d_in[10];
  const float* Wgb  = (const float*)d_in[11];
  const float* bgb  = (const float*)d_in[12];
  const float* Wg   = (const float*)d_in[13];
  const float* bg   = (const float*)d_in[14];
  const float* Wo   = (const float*)d_in[15];
  const float* bo   = (const float*)d_in[16];

  char* ws = (char*)d_ws;
  _Float16* at_  = (_Float16*)(ws + 0);
  _Float16* bt_  = (_Float16*)(ws + 37748736);
  _Float16* gate = (_Float16*)(ws + 75497472);
  _Float16* o16  = (_Float16*)(ws + 113246208);
  _Float16* wf   = (_Float16*)(ws + 188743680);

  hipLaunchKernelGGL(k0_wt, dim3(6), dim3(256), 0, stream, Wa, Wga, Wb, Wgb, Wg, Wo, wf);
  hipLaunchKernelGGL(k2_ln_gemm, dim3(2304), dim3(256), 0, stream,
                     z, l1g, l1b, wf, ba, bga, bb, bgb, bg, at_, bt_, gate);
  hipLaunchKernelGGL(k3_tri, dim3(9, 128), dim3(256), 0, stream, at_, bt_, o16);
  hipLaunchKernelGGL(k4_out, dim3(2304), dim3(256), 0, stream,
                     o16, gate, l2g, l2b, wf + 5*16384, bo, (float*)d_out);
}